// Round 7
// baseline (673.245 us; speedup 1.0000x reference)
//
#include <hip/hip_runtime.h>
#include <math.h>

#define BB 4
#define CC 512
#define HH 48
#define WW 48
#define NN 2304      // H*W
#define DDQ 64       // C/8
#define LDSP 72      // padded LDS stride for 64-wide tiles (fp16 elems)
#define PW 50        // padded image width (W+2)
#define PROWS 2500   // (H+2)*(W+2)

typedef __attribute__((ext_vector_type(4))) float f32x4;
typedef __attribute__((ext_vector_type(8))) _Float16 half8;
typedef __attribute__((ext_vector_type(4))) _Float16 half4;

__device__ __forceinline__ int imax(int a, int b) { return a > b ? a : b; }
__device__ __forceinline__ int imin(int a, int b) { return a < b ? a : b; }
__device__ __forceinline__ int prow(int m) {
    int h = m / WW, w = m - h * WW;
    return (h + 1) * PW + (w + 1);
}

// ---- async global->LDS, 16B per lane, wave-uniform LDS base ----
typedef __attribute__((address_space(1))) unsigned int g_u32;
typedef __attribute__((address_space(3))) unsigned int l_u32;
__device__ __forceinline__ void gl16(const _Float16* g, _Float16* l) {
    __builtin_amdgcn_global_load_lds((g_u32*)g, (l_u32*)l, 16, 0, 0);
}

// ===========================================================================
// Big-tile GEMM core: 128(M) x 64(N), BK=64 halves, 256 threads, XOR swizzle.
// ===========================================================================
#define BWAVE_IDX()                                  \
    int tid = threadIdx.x;                           \
    int wave = tid >> 6, lane = tid & 63;            \
    int wm = (wave >> 1) * 64, wn = (wave & 1) * 32; \
    int x = lane & 15, qq = lane >> 4;

__device__ __forceinline__ half8 fragld(const _Float16* T, int r, int c) {
    int kb = c ^ (r & 7);
    return *(const half8*)(T + r * 64 + kb * 8);
}

__device__ __forceinline__ void btile(const _Float16* As, const _Float16* Bs,
                                      f32x4 acc[4][2], int wm, int wn, int x, int qq) {
#pragma unroll
    for (int ks = 0; ks < 2; ++ks) {
        int c = ks * 4 + qq;
        half8 a0 = fragld(As, wm + x, c);
        half8 a1 = fragld(As, wm + 16 + x, c);
        half8 a2 = fragld(As, wm + 32 + x, c);
        half8 a3 = fragld(As, wm + 48 + x, c);
        half8 b0 = fragld(Bs, wn + x, c);
        half8 b1 = fragld(Bs, wn + 16 + x, c);
        acc[0][0] = __builtin_amdgcn_mfma_f32_16x16x32_f16(a0, b0, acc[0][0], 0, 0, 0);
        acc[0][1] = __builtin_amdgcn_mfma_f32_16x16x32_f16(a0, b1, acc[0][1], 0, 0, 0);
        acc[1][0] = __builtin_amdgcn_mfma_f32_16x16x32_f16(a1, b0, acc[1][0], 0, 0, 0);
        acc[1][1] = __builtin_amdgcn_mfma_f32_16x16x32_f16(a1, b1, acc[1][1], 0, 0, 0);
        acc[2][0] = __builtin_amdgcn_mfma_f32_16x16x32_f16(a2, b0, acc[2][0], 0, 0, 0);
        acc[2][1] = __builtin_amdgcn_mfma_f32_16x16x32_f16(a2, b1, acc[2][1], 0, 0, 0);
        acc[3][0] = __builtin_amdgcn_mfma_f32_16x16x32_f16(a3, b0, acc[3][0], 0, 0, 0);
        acc[3][1] = __builtin_amdgcn_mfma_f32_16x16x32_f16(a3, b1, acc[3][1], 0, 0, 0);
    }
}

#define BACC_INIT()                                         \
    f32x4 zf = {0.f, 0.f, 0.f, 0.f};                        \
    f32x4 acc[4][2];                                        \
    _Pragma("unroll") for (int i_ = 0; i_ < 4; ++i_) {      \
        acc[i_][0] = zf; acc[i_][1] = zf; }

#define SLOT_A(i) int sb = (wave * 4 + (i)) * 64; int s = sb + lane; \
                  int r = s >> 3, kb = s & 7; int koff = ((kb ^ (r & 7)) << 3);
#define SLOT_B(i) int sb = (wave * 2 + (i)) * 64; int s = sb + lane; \
                  int r = s >> 3, kb = s & 7; int koff = ((kb ^ (r & 7)) << 3);

// ===========================================================================
// small 64^2 helpers
// ===========================================================================
__device__ __forceinline__ void stage_rows(_Float16* dst, const _Float16* __restrict__ src,
                                           int ld, int row0, int k0, int tid) {
#pragma unroll
    for (int i = 0; i < 2; ++i) {
        int s = tid * 2 + i;
        int r = s >> 3, off = (s & 7) << 3;
        *(half8*)(dst + r * LDSP + off) =
            *(const half8*)(src + (size_t)(row0 + r) * ld + k0 + off);
    }
}
__device__ __forceinline__ void mfma_tile(const _Float16* As, const _Float16* Bs,
                                          f32x4 acc[2][2], int wm, int wn, int x, int qq) {
#pragma unroll
    for (int ks = 0; ks < 2; ++ks) {
        int kof = ks * 32 + qq * 8;
        half8 a0 = *(const half8*)(As + (wm + x) * LDSP + kof);
        half8 a1 = *(const half8*)(As + (wm + 16 + x) * LDSP + kof);
        half8 b0 = *(const half8*)(Bs + (wn + x) * LDSP + kof);
        half8 b1 = *(const half8*)(Bs + (wn + 16 + x) * LDSP + kof);
        acc[0][0] = __builtin_amdgcn_mfma_f32_16x16x32_f16(a0, b0, acc[0][0], 0, 0, 0);
        acc[0][1] = __builtin_amdgcn_mfma_f32_16x16x32_f16(a0, b1, acc[0][1], 0, 0, 0);
        acc[1][0] = __builtin_amdgcn_mfma_f32_16x16x32_f16(a1, b0, acc[1][0], 0, 0, 0);
        acc[1][1] = __builtin_amdgcn_mfma_f32_16x16x32_f16(a1, b1, acc[1][1], 0, 0, 0);
    }
}
#define WAVE_IDX()                             \
    int tid = threadIdx.x;                     \
    int wave = tid >> 6, lane = tid & 63;      \
    int wm = (wave >> 1) * 32, wn = (wave & 1) * 32; \
    int x = lane & 15, qq = lane >> 4;
#define ACC_INIT()                             \
    f32x4 zf = {0.f, 0.f, 0.f, 0.f};           \
    f32x4 acc[2][2];                           \
    acc[0][0] = zf; acc[0][1] = zf; acc[1][0] = zf; acc[1][1] = zf;

// ------------------------- prep kernels -------------------------
__global__ __launch_bounds__(256) void k_cast_multi(const float* __restrict__ s0,
                                                    const float* __restrict__ s1,
                                                    const float* __restrict__ s2,
                                                    _Float16* __restrict__ d0,
                                                    _Float16* __restrict__ d1,
                                                    _Float16* __restrict__ d2, int n) {
    const float* s = blockIdx.y == 0 ? s0 : (blockIdx.y == 1 ? s1 : s2);
    _Float16* d = blockIdx.y == 0 ? d0 : (blockIdx.y == 1 ? d1 : d2);
    for (int i = blockIdx.x * 256 + threadIdx.x; i < n; i += gridDim.x * 256)
        d[i] = (_Float16)s[i];
}

__global__ __launch_bounds__(256) void k_repack_conv2(const float* __restrict__ w1,
                                                      const float* __restrict__ w2,
                                                      _Float16* __restrict__ d1,
                                                      _Float16* __restrict__ d2) {
    const float* w = blockIdx.y ? w2 : w1;
    _Float16* dst = blockIdx.y ? d2 : d1;
    int i = blockIdx.x * 256 + threadIdx.x;
    if (i >= 9 * CC * CC) return;
    int r = i / (CC * CC);
    int rem = i - r * CC * CC;
    int co = rem / CC, ci = rem - (rem / CC) * CC;
    dst[i] = (_Float16)w[((size_t)co * CC + ci) * 9 + r];
}

__global__ __launch_bounds__(256) void k_transpose_x(const float* __restrict__ x,
                                                     _Float16* __restrict__ xT) {
    __shared__ float tile[32][33];
    int b = blockIdx.z;
    int c0 = blockIdx.y * 32, n0 = blockIdx.x * 32;
    int tx = threadIdx.x & 31, ty = threadIdx.x >> 5;
    const float* xb = x + (size_t)b * CC * NN;
#pragma unroll
    for (int rr = 0; rr < 32; rr += 8)
        tile[ty + rr][tx] = xb[(size_t)(c0 + ty + rr) * NN + n0 + tx];
    __syncthreads();
    _Float16* xTb = xT + (size_t)b * NN * CC;
#pragma unroll
    for (int rr = 0; rr < 32; rr += 8)
        xTb[(size_t)(n0 + ty + rr) * CC + c0 + tx] = (_Float16)tile[tx][ty + rr];
}

// ------------------------- q/k projection -------------------------
__global__ __launch_bounds__(256) void k_qkproj(const _Float16* __restrict__ Wq,
                                                const _Float16* __restrict__ Wk,
                                                const float* __restrict__ bq,
                                                const float* __restrict__ bk,
                                                const _Float16* __restrict__ xT,
                                                _Float16* __restrict__ qT,
                                                _Float16* __restrict__ kT) {
    __shared__ _Float16 As[64 * LDSP];
    __shared__ _Float16 Bs[64 * LDSP];
    WAVE_IDX();
    int j0 = blockIdx.x * 64, b = blockIdx.z;
    const _Float16* Wp = blockIdx.y ? Wk : Wq;
    const float* bias = blockIdx.y ? bk : bq;
    _Float16* outT = blockIdx.y ? kT : qT;
    const _Float16* xTb = xT + (size_t)b * NN * CC;
    ACC_INIT();
    for (int kc = 0; kc < CC; kc += 64) {
        stage_rows(As, Wp, CC, 0, kc, tid);
        stage_rows(Bs, xTb, CC, j0, kc, tid);
        __syncthreads();
        mfma_tile(As, Bs, acc, wm, wn, x, qq);
        __syncthreads();
    }
#pragma unroll
    for (int ms = 0; ms < 2; ++ms) {
        int R0 = wm + ms * 16 + qq * 4;
#pragma unroll
        for (int ns = 0; ns < 2; ++ns) {
            int Ccol = j0 + wn + ns * 16 + x;
            half4 t;
            t.x = (_Float16)(acc[ms][ns][0] + bias[R0 + 0]);
            t.y = (_Float16)(acc[ms][ns][1] + bias[R0 + 1]);
            t.z = (_Float16)(acc[ms][ns][2] + bias[R0 + 2]);
            t.w = (_Float16)(acc[ms][ns][3] + bias[R0 + 3]);
            *(half4*)(outT + ((size_t)b * NN + Ccol) * DDQ + R0) = t;
        }
    }
}

// ------------------------- C x C GEMM, big tile -------------------------
template <int EPI, int PAD>
__global__ __launch_bounds__(256) void k_cgemm(const _Float16* __restrict__ W,
                                               const float* __restrict__ bias,
                                               const _Float16* __restrict__ Bsrc,
                                               const float* __restrict__ gate,
                                               _Float16* __restrict__ out) {
    __shared__ _Float16 As[128 * 64];
    __shared__ _Float16 Bs[64 * 64];
    BWAVE_IDX();
    int j0 = blockIdx.x * 64, i0 = blockIdx.y * 128, b = blockIdx.z;
    const _Float16* Bb = Bsrc + (size_t)b * (PAD ? (size_t)PROWS * CC : (size_t)NN * CC);

    const _Float16* aSrc[4]; int aOf[4];
#pragma unroll
    for (int i = 0; i < 4; ++i) {
        SLOT_A(i);
        aSrc[i] = W + (size_t)(i0 + r) * CC + koff;
        aOf[i] = sb * 8;
    }
    const _Float16* bSrc[2]; int bOf[2];
#pragma unroll
    for (int i = 0; i < 2; ++i) {
        SLOT_B(i);
        int row = PAD ? prow(j0 + r) : (j0 + r);
        bSrc[i] = Bb + (size_t)row * CC + koff;
        bOf[i] = sb * 8;
    }
    BACC_INIT();
    for (int kc = 0; kc < CC; kc += 64) {
        __syncthreads();
#pragma unroll
        for (int i = 0; i < 4; ++i) gl16(aSrc[i] + kc, As + aOf[i]);
#pragma unroll
        for (int i = 0; i < 2; ++i) gl16(bSrc[i] + kc, Bs + bOf[i]);
        __syncthreads();
        btile(As, Bs, acc, wm, wn, x, qq);
    }
#pragma unroll
    for (int mt = 0; mt < 4; ++mt) {
        int R0 = i0 + wm + mt * 16 + qq * 4;
#pragma unroll
        for (int nt = 0; nt < 2; ++nt) {
            int Ccol = j0 + wn + nt * 16 + x;
#pragma unroll
            for (int e = 0; e < 4; ++e) {
                float v = acc[mt][nt][e] + bias[R0 + e];
                size_t idx = ((size_t)b * CC + R0 + e) * NN + Ccol;
                if (EPI == 1) v = gate[idx] / (1.f + __expf(-v));
                out[idx] = (_Float16)v;
            }
        }
    }
}

// ------------------------- fused energy + masked softmax -------------------------
// One block per 64 query rows. attn fp16 [b][m][n], stride NN. Two-pass softmax
// WITHOUT max subtraction (|energy| << 88, fp32 exp cannot overflow; ratios are
// mathematically identical to the max-subtracted reference). No -inf sentinels,
// no online rescale, no LDS type-punning.
__global__ __launch_bounds__(256) void k_fused_sm(const _Float16* __restrict__ qT,
                                                  const _Float16* __restrict__ kT,
                                                  _Float16* __restrict__ attn, int rad) {
    __shared__ _Float16 qs[64 * LDSP];
    __shared__ _Float16 ks[64 * LDSP];
    __shared__ float Ef[64][68];      // exp(energy) (or 0 if masked) for current chunk
    __shared__ _Float16 Eh[64 * 72];  // normalized fp16 weights staging (pass 2)
    __shared__ float psum[256];
    __shared__ float linvS[64];
    WAVE_IDX();
    int i0 = blockIdx.x * 64, b = blockIdx.y;

    int klo = 0, khi = NN;
    if (rad > 0) {
        int hlo = i0 / WW, hhi = (i0 + 63) / WW;
        int h2lo = imax(0, hlo - rad), h2hi = imin(HH - 1, hhi + rad);
        klo = (h2lo * WW) & ~63;
        khi = imin(NN, ((h2hi + 1) * WW + 63) & ~63);
    }

    // per-lane query coords for the 8 C-rows this lane holds
    int hm8[8], cm8[8];
#pragma unroll
    for (int ms = 0; ms < 2; ++ms)
#pragma unroll
        for (int e = 0; e < 4; ++e) {
            int gm = i0 + wm + ms * 16 + qq * 4 + e;
            hm8[ms * 4 + e] = gm / WW;
            cm8[ms * 4 + e] = gm % WW;
        }

    stage_rows(qs, qT + (size_t)b * NN * DDQ, DDQ, i0, 0, tid);

    float l_i = 0.f;   // row sum, live in threads 0..63 (row = tid)
    const _Float16* kTb = kT + (size_t)b * NN * DDQ;

    // ---------------- pass 1: row sums of exp(e) ----------------
    for (int j0 = klo; j0 < khi; j0 += 64) {
        __syncthreads();
        stage_rows(ks, kTb, DDQ, j0, 0, tid);
        __syncthreads();
        ACC_INIT();
        mfma_tile(qs, ks, acc, wm, wn, x, qq);
#pragma unroll
        for (int ns = 0; ns < 2; ++ns) {
            int col = wn + ns * 16 + x;
            int gn = j0 + col;
            int hn = gn / WW, cn = gn % WW;
#pragma unroll
            for (int ms = 0; ms < 2; ++ms)
#pragma unroll
                for (int e = 0; e < 4; ++e) {
                    int ri = ms * 4 + e;
                    bool valid = true;
                    if (rad > 0) {
                        int dh = hm8[ri] - hn; if (dh < 0) dh = -dh;
                        int dc = cm8[ri] - cn; if (dc < 0) dc = -dc;
                        valid = (dh <= rad) && (dc <= rad);
                    }
                    Ef[wm + ms * 16 + qq * 4 + e][col] =
                        valid ? __expf(acc[ms][ns][e]) : 0.f;
                }
        }
        __syncthreads();
        {
            int r = tid >> 2, qtr = tid & 3;
            float s = 0.f;
#pragma unroll
            for (int j = 0; j < 16; ++j) s += Ef[r][qtr * 16 + j];
            psum[tid] = s;
        }
        __syncthreads();
        if (tid < 64)
            l_i += psum[tid * 4] + psum[tid * 4 + 1] + psum[tid * 4 + 2] + psum[tid * 4 + 3];
    }
    if (tid < 64) linvS[tid] = 1.f / fmaxf(l_i, 1e-30f);

    // ---------------- pass 2: recompute, normalize, write fp16 ----------------
    for (int j0 = klo; j0 < khi; j0 += 64) {
        __syncthreads();
        stage_rows(ks, kTb, DDQ, j0, 0, tid);
        __syncthreads();
        ACC_INIT();
        mfma_tile(qs, ks, acc, wm, wn, x, qq);
#pragma unroll
        for (int ns = 0; ns < 2; ++ns) {
            int col = wn + ns * 16 + x;
            int gn = j0 + col;
            int hn = gn / WW, cn = gn % WW;
#pragma unroll
            for (int ms = 0; ms < 2; ++ms)
#pragma unroll
                for (int e = 0; e < 4; ++e) {
                    int ri = ms * 4 + e;
                    int row = wm + ms * 16 + qq * 4 + e;
                    bool valid = true;
                    if (rad > 0) {
                        int dh = hm8[ri] - hn; if (dh < 0) dh = -dh;
                        int dc = cm8[ri] - cn; if (dc < 0) dc = -dc;
                        valid = (dh <= rad) && (dc <= rad);
                    }
                    float w = valid ? __expf(acc[ms][ns][e]) * linvS[row] : 0.f;
                    Eh[row * 72 + col] = (_Float16)w;
                }
        }
        __syncthreads();
#pragma unroll
        for (int t = 0; t < 2; ++t) {
            int s = tid + t * 256;
            int r = s >> 3, cg = (s & 7) << 3;
            *(half8*)(attn + ((size_t)b * NN + i0 + r) * NN + j0 + cg) =
                *(const half8*)(Eh + r * 72 + cg);
        }
    }
}

// ------------------------- attention apply, big tile -------------------------
__global__ __launch_bounds__(256) void k_attn(const _Float16* __restrict__ A,
                                              const _Float16* __restrict__ attn,
                                              const float* __restrict__ res,
                                              const float* __restrict__ gamma,
                                              float* __restrict__ outF,
                                              _Float16* __restrict__ outT, int rad) {
    __shared__ _Float16 As[128 * 64];
    __shared__ _Float16 Bs[64 * 64];
    BWAVE_IDX();
    int j0 = blockIdx.x * 64, i0 = blockIdx.y * 128, b = blockIdx.z;
    int klo = 0, khi = NN;
    if (rad > 0) {
        int hlo = j0 / WW, hhi = (j0 + 63) / WW;
        int h2lo = imax(0, hlo - rad), h2hi = imin(HH - 1, hhi + rad);
        klo = (h2lo * WW) & ~63;
        khi = imin(NN, ((h2hi + 1) * WW + 63) & ~63);
    }
    const _Float16* Ab = A + (size_t)b * CC * NN;
    const _Float16* Tb = attn + (size_t)b * NN * NN;

    const _Float16* aSrc[4]; int aOf[4];
#pragma unroll
    for (int i = 0; i < 4; ++i) {
        SLOT_A(i);
        aSrc[i] = Ab + (size_t)(i0 + r) * NN + koff;
        aOf[i] = sb * 8;
    }
    const _Float16* bSrc[2]; int bOf[2];
#pragma unroll
    for (int i = 0; i < 2; ++i) {
        SLOT_B(i);
        bSrc[i] = Tb + (size_t)(j0 + r) * NN + koff;
        bOf[i] = sb * 8;
    }
    BACC_INIT();
    for (int kc = klo; kc < khi; kc += 64) {
        __syncthreads();
#pragma unroll
        for (int i = 0; i < 4; ++i) gl16(aSrc[i] + kc, As + aOf[i]);
#pragma unroll
        for (int i = 0; i < 2; ++i) gl16(bSrc[i] + kc, Bs + bOf[i]);
        __syncthreads();
        btile(As, Bs, acc, wm, wn, x, qq);
    }
    float g = gamma[0];
#pragma unroll
    for (int mt = 0; mt < 4; ++mt) {
        int R0 = i0 + wm + mt * 16 + qq * 4;
#pragma unroll
        for (int nt = 0; nt < 2; ++nt) {
            int Ccol = j0 + wn + nt * 16 + x;
            float v[4];
#pragma unroll
            for (int e = 0; e < 4; ++e)
                v[e] = g * acc[mt][nt][e] + res[((size_t)b * CC + R0 + e) * NN + Ccol];
            if (outT) {
                half4 t;
                t.x = (_Float16)v[0]; t.y = (_Float16)v[1];
                t.z = (_Float16)v[2]; t.w = (_Float16)v[3];
                *(half4*)(outT + ((size_t)b * PROWS + prow(Ccol)) * CC + R0) = t;
            }
            if (outF) {
#pragma unroll
                for (int e = 0; e < 4; ++e)
                    outF[((size_t)b * CC + R0 + e) * NN + Ccol] = v[e];
            }
        }
    }
}

// ------------------------- 3x3 conv, big tile, fused BN+ReLU -------------------------
__global__ __launch_bounds__(256) void k_conv3(const _Float16* __restrict__ Arep,
                                               const _Float16* __restrict__ Tpad,
                                               const float* __restrict__ bng,
                                               const float* __restrict__ bnb,
                                               const float* __restrict__ bnm,
                                               const float* __restrict__ bnv,
                                               float* __restrict__ outF,
                                               _Float16* __restrict__ outT) {
    __shared__ _Float16 As[128 * 64];
    __shared__ _Float16 Bs[64 * 64];
    BWAVE_IDX();
    int j0 = blockIdx.x * 64, i0 = blockIdx.y * 128, b = blockIdx.z;
    const _Float16* Tb = Tpad + (size_t)b * PROWS * CC;

    size_t aRow[4]; int aOf[4];
#pragma unroll
    for (int i = 0; i < 4; ++i) {
        SLOT_A(i);
        aRow[i] = (size_t)(i0 + r) * CC + koff;
        aOf[i] = sb * 8;
    }
    int bPr[2], bKoff[2], bOf[2];
#pragma unroll
    for (int i = 0; i < 2; ++i) {
        SLOT_B(i);
        bPr[i] = prow(j0 + r);
        bKoff[i] = koff;
        bOf[i] = sb * 8;
    }
    BACC_INIT();
#pragma unroll
    for (int rt = 0; rt < 9; ++rt) {
        int dh = rt / 3 - 1, dw = rt - (rt / 3) * 3 - 1;
        int shift = dh * PW + dw;
        const _Float16* Ar = Arep + (size_t)rt * CC * CC;
        for (int ci0 = 0; ci0 < CC; ci0 += 64) {
            __syncthreads();
#pragma unroll
            for (int i = 0; i < 4; ++i) gl16(Ar + aRow[i] + ci0, As + aOf[i]);
#pragma unroll
            for (int i = 0; i < 2; ++i)
                gl16(Tb + (size_t)(bPr[i] + shift) * CC + ci0 + bKoff[i], Bs + bOf[i]);
            __syncthreads();
            btile(As, Bs, acc, wm, wn, x, qq);
        }
    }
#pragma unroll
    for (int mt = 0; mt < 4; ++mt) {
        int R0 = i0 + wm + mt * 16 + qq * 4;
        float sc[4], sh[4];
#pragma unroll
        for (int e = 0; e < 4; ++e) {
            sc[e] = bng[R0 + e] * rsqrtf(bnv[R0 + e] + 1e-5f);
            sh[e] = bnb[R0 + e] - bnm[R0 + e] * sc[e];
        }
#pragma unroll
        for (int nt = 0; nt < 2; ++nt) {
            int Ccol = j0 + wn + nt * 16 + x;
            float v[4];
#pragma unroll
            for (int e = 0; e < 4; ++e) {
                float t = acc[mt][nt][e] * sc[e] + sh[e];
                v[e] = t > 0.f ? t : 0.f;
                outF[((size_t)b * CC + R0 + e) * NN + Ccol] = v[e];
            }
            half4 t4;
            t4.x = (_Float16)v[0]; t4.y = (_Float16)v[1];
            t4.z = (_Float16)v[2]; t4.w = (_Float16)v[3];
            *(half4*)(outT + ((size_t)b * PROWS + prow(Ccol)) * CC + R0) = t4;
        }
    }
}

// ---------------------------------------------------------------------------
extern "C" void kernel_launch(void* const* d_in, const int* in_sizes, int n_in,
                              void* d_out, int out_size, void* d_ws, size_t ws_size,
                              hipStream_t stream) {
    const float* xin  = (const float*)d_in[0];
    const float* Wq   = (const float*)d_in[1];
    const float* bq   = (const float*)d_in[2];
    const float* Wk   = (const float*)d_in[3];
    const float* bk   = (const float*)d_in[4];
    const float* Wv   = (const float*)d_in[5];
    const float* bv   = (const float*)d_in[6];
    const float* c1w  = (const float*)d_in[7];
    const float* bn1w = (const float*)d_in[8];
    const float* bn1b = (const float*)d_in[9];
    const float* bn1m = (const float*)d_in[10];
    const float* bn1v = (const float*)d_in[11];
    const float* c2w  = (const float*)d_in[12];
    const float* bn2w = (const float*)d_in[13];
    const float* bn2b = (const float*)d_in[14];
    const float* bn2m = (const float*)d_in[15];
    const float* bn2v = (const float*)d_in[16];
    const float* s1w  = (const float*)d_in[17];
    const float* s1b  = (const float*)d_in[18];
    const float* s2w  = (const float*)d_in[19];
    const float* s2b  = (const float*)d_in[20];
    const float* gamma  = (const float*)d_in[21];
    const float* gamma1 = (const float*)d_in[22];
    const float* gamma2 = (const float*)d_in[23];

    float* out = (float*)d_out;

    char* p = (char*)d_ws;
    _Float16* attn  = (_Float16*)p; p += (size_t)BB * NN * NN * 2;      // 42.5 MB
    _Float16* xT    = (_Float16*)p; p += (size_t)BB * NN * CC * 2;      // 9.4 MB
    _Float16* qT    = (_Float16*)p; p += (size_t)BB * NN * DDQ * 2;
    _Float16* kT    = (_Float16*)p; p += (size_t)BB * NN * DDQ * 2;
    _Float16* vsB   = (_Float16*)p; p += (size_t)BB * CC * NN * 2;      // 9.4 MB
    _Float16* TattnP= (_Float16*)p; p += (size_t)BB * PROWS * CC * 2;   // 10.2 MB
    _Float16* TconvP= (_Float16*)p; p += (size_t)BB * PROWS * CC * 2;   // 10.2 MB
    float*    rR    = (float*)p;    p += (size_t)BB * CC * NN * 4;      // 18.9 MB
    _Float16* wq_h  = (_Float16*)p; p += (size_t)DDQ * CC * 2;
    _Float16* wk_h  = (_Float16*)p; p += (size_t)DDQ * CC * 2;
    _Float16* wv_h  = (_Float16*)p; p += (size_t)CC * CC * 2;
    _Float16* s1_h  = (_Float16*)p; p += (size_t)CC * CC * 2;
    _Float16* s2_h  = (_Float16*)p; p += (size_t)CC * CC * 2;
    _Float16* crep1 = (_Float16*)p; p += (size_t)9 * CC * CC * 2;
    _Float16* crep2 = (_Float16*)p; p += (size_t)9 * CC * CC * 2;

    dim3 blk(256);

    // zero padded activation borders (taps read them)
    hipMemsetAsync(TattnP, 0, (size_t)BB * PROWS * CC * 2, stream);
    hipMemsetAsync(TconvP, 0, (size_t)BB * PROWS * CC * 2, stream);

    // ---- prep ----
    k_cast_multi<<<dim3(128, 2), blk, 0, stream>>>(Wq, Wk, nullptr, wq_h, wk_h, nullptr, DDQ * CC);
    k_cast_multi<<<dim3(1024, 3), blk, 0, stream>>>(Wv, s1w, s2w, wv_h, s1_h, s2_h, CC * CC);
    k_repack_conv2<<<dim3((9 * CC * CC + 255) / 256, 2), blk, 0, stream>>>(c1w, c2w, crep1, crep2);
    k_transpose_x<<<dim3(NN / 32, CC / 32, BB), blk, 0, stream>>>(xin, xT);

    dim3 gQK(NN / 64, 2, BB);
    dim3 gSm(NN / 64, BB);              // fused energy+softmax: (36, 4)
    dim3 gBig(NN / 64, CC / 128, BB);   // (36, 4, 4) = 576 blocks

    // projections
    k_qkproj<<<gQK, blk, 0, stream>>>(wq_h, wk_h, bq, bk, xT, qT, kT);
    k_cgemm<0, 0><<<gBig, blk, 0, stream>>>(wv_h, bv, xT, nullptr, vsB);

    // ---- stage 0: dense attention ----
    k_fused_sm<<<gSm, blk, 0, stream>>>(qT, kT, attn, -1);
    k_attn<<<gBig, blk, 0, stream>>>(vsB, attn, xin, gamma, nullptr, TattnP, -1);
    k_conv3<<<gBig, blk, 0, stream>>>(crep1, TattnP, bn1w, bn1b, bn1m, bn1v, rR, TconvP);

    // ---- stage 1: radius-6 masked attention ----
    k_cgemm<1, 1><<<gBig, blk, 0, stream>>>(s1_h, s1b, TconvP, rR, vsB);
    k_fused_sm<<<gSm, blk, 0, stream>>>(qT, kT, attn, 6);
    k_attn<<<gBig, blk, 0, stream>>>(vsB, attn, rR, gamma1, nullptr, TattnP, 6);
    k_conv3<<<gBig, blk, 0, stream>>>(crep2, TattnP, bn2w, bn2b, bn2m, bn2v, rR, TconvP);

    // ---- stage 2: radius-12 masked attention ----
    k_cgemm<1, 1><<<gBig, blk, 0, stream>>>(s2_h, s2b, TconvP, rR, vsB);
    k_fused_sm<<<gSm, blk, 0, stream>>>(qT, kT, attn, 12);
    k_attn<<<gBig, blk, 0, stream>>>(vsB, attn, rR, gamma2, out, nullptr, 12);
}

// Round 8
// 496.679 us; speedup vs baseline: 1.3555x; 1.3555x over previous
//
#include <hip/hip_runtime.h>
#include <math.h>

#define BB 4
#define CC 512
#define HH 48
#define WW 48
#define NN 2304      // H*W
#define DDQ 64       // C/8
#define LDSP 72      // padded LDS stride for 64-wide tiles (fp16 elems)
#define PW 50        // padded image width (W+2)
#define PROWS 2500   // (H+2)*(W+2)

typedef __attribute__((ext_vector_type(4))) float f32x4;
typedef __attribute__((ext_vector_type(8))) _Float16 half8;
typedef __attribute__((ext_vector_type(4))) _Float16 half4;
typedef __attribute__((ext_vector_type(8))) short bf16x8;

__device__ __forceinline__ int imax(int a, int b) { return a > b ? a : b; }
__device__ __forceinline__ int imin(int a, int b) { return a < b ? a : b; }
__device__ __forceinline__ int prow(int m) {
    int h = m / WW, w = m - h * WW;
    return (h + 1) * PW + (w + 1);
}
__device__ __forceinline__ unsigned short f2bf(float f) {
    unsigned u = __float_as_uint(f);
    u += 0x7fffu + ((u >> 16) & 1u);   // RNE
    return (unsigned short)(u >> 16);
}
__device__ __forceinline__ float bf2f(unsigned short s) {
    unsigned u = ((unsigned)s) << 16;
    return __uint_as_float(u);
}

// ---- async global->LDS, 16B per lane, wave-uniform LDS base ----
typedef __attribute__((address_space(1))) unsigned int g_u32;
typedef __attribute__((address_space(3))) unsigned int l_u32;
__device__ __forceinline__ void gl16(const void* g, void* l) {
    __builtin_amdgcn_global_load_lds((const g_u32*)g, (l_u32*)l, 16, 0, 0);
}

// ===========================================================================
// Big-tile GEMM core: 128(M) x 64(N), BK=64 elems, 256 threads, XOR swizzle.
// ===========================================================================
#define BWAVE_IDX()                                  \
    int tid = threadIdx.x;                           \
    int wave = tid >> 6, lane = tid & 63;            \
    int wm = (wave >> 1) * 64, wn = (wave & 1) * 32; \
    int x = lane & 15, qq = lane >> 4;

__device__ __forceinline__ half8 fragld(const _Float16* T, int r, int c) {
    int kb = c ^ (r & 7);
    return *(const half8*)(T + r * 64 + kb * 8);
}
__device__ __forceinline__ bf16x8 fragld_b(const unsigned short* T, int r, int c) {
    int kb = c ^ (r & 7);
    return *(const bf16x8*)(T + r * 64 + kb * 8);
}

__device__ __forceinline__ void btile(const _Float16* As, const _Float16* Bs,
                                      f32x4 acc[4][2], int wm, int wn, int x, int qq) {
#pragma unroll
    for (int ks = 0; ks < 2; ++ks) {
        int c = ks * 4 + qq;
        half8 a0 = fragld(As, wm + x, c);
        half8 a1 = fragld(As, wm + 16 + x, c);
        half8 a2 = fragld(As, wm + 32 + x, c);
        half8 a3 = fragld(As, wm + 48 + x, c);
        half8 b0 = fragld(Bs, wn + x, c);
        half8 b1 = fragld(Bs, wn + 16 + x, c);
        acc[0][0] = __builtin_amdgcn_mfma_f32_16x16x32_f16(a0, b0, acc[0][0], 0, 0, 0);
        acc[0][1] = __builtin_amdgcn_mfma_f32_16x16x32_f16(a0, b1, acc[0][1], 0, 0, 0);
        acc[1][0] = __builtin_amdgcn_mfma_f32_16x16x32_f16(a1, b0, acc[1][0], 0, 0, 0);
        acc[1][1] = __builtin_amdgcn_mfma_f32_16x16x32_f16(a1, b1, acc[1][1], 0, 0, 0);
        acc[2][0] = __builtin_amdgcn_mfma_f32_16x16x32_f16(a2, b0, acc[2][0], 0, 0, 0);
        acc[2][1] = __builtin_amdgcn_mfma_f32_16x16x32_f16(a2, b1, acc[2][1], 0, 0, 0);
        acc[3][0] = __builtin_amdgcn_mfma_f32_16x16x32_f16(a3, b0, acc[3][0], 0, 0, 0);
        acc[3][1] = __builtin_amdgcn_mfma_f32_16x16x32_f16(a3, b1, acc[3][1], 0, 0, 0);
    }
}
__device__ __forceinline__ void btile_b(const unsigned short* As, const unsigned short* Bs,
                                        f32x4 acc[4][2], int wm, int wn, int x, int qq) {
#pragma unroll
    for (int ks = 0; ks < 2; ++ks) {
        int c = ks * 4 + qq;
        bf16x8 a0 = fragld_b(As, wm + x, c);
        bf16x8 a1 = fragld_b(As, wm + 16 + x, c);
        bf16x8 a2 = fragld_b(As, wm + 32 + x, c);
        bf16x8 a3 = fragld_b(As, wm + 48 + x, c);
        bf16x8 b0 = fragld_b(Bs, wn + x, c);
        bf16x8 b1 = fragld_b(Bs, wn + 16 + x, c);
        acc[0][0] = __builtin_amdgcn_mfma_f32_16x16x32_bf16(a0, b0, acc[0][0], 0, 0, 0);
        acc[0][1] = __builtin_amdgcn_mfma_f32_16x16x32_bf16(a0, b1, acc[0][1], 0, 0, 0);
        acc[1][0] = __builtin_amdgcn_mfma_f32_16x16x32_bf16(a1, b0, acc[1][0], 0, 0, 0);
        acc[1][1] = __builtin_amdgcn_mfma_f32_16x16x32_bf16(a1, b1, acc[1][1], 0, 0, 0);
        acc[2][0] = __builtin_amdgcn_mfma_f32_16x16x32_bf16(a2, b0, acc[2][0], 0, 0, 0);
        acc[2][1] = __builtin_amdgcn_mfma_f32_16x16x32_bf16(a2, b1, acc[2][1], 0, 0, 0);
        acc[3][0] = __builtin_amdgcn_mfma_f32_16x16x32_bf16(a3, b0, acc[3][0], 0, 0, 0);
        acc[3][1] = __builtin_amdgcn_mfma_f32_16x16x32_bf16(a3, b1, acc[3][1], 0, 0, 0);
    }
}

#define BACC_INIT()                                         \
    f32x4 zf = {0.f, 0.f, 0.f, 0.f};                        \
    f32x4 acc[4][2];                                        \
    _Pragma("unroll") for (int i_ = 0; i_ < 4; ++i_) {      \
        acc[i_][0] = zf; acc[i_][1] = zf; }

#define SLOT_A(i) int sb = (wave * 4 + (i)) * 64; int s = sb + lane; \
                  int r = s >> 3, kb = s & 7; int koff = ((kb ^ (r & 7)) << 3);
#define SLOT_B(i) int sb = (wave * 2 + (i)) * 64; int s = sb + lane; \
                  int r = s >> 3, kb = s & 7; int koff = ((kb ^ (r & 7)) << 3);

// ===========================================================================
// small 64^2 helpers
// ===========================================================================
__device__ __forceinline__ void stage_rows(_Float16* dst, const _Float16* __restrict__ src,
                                           int ld, int row0, int k0, int tid) {
#pragma unroll
    for (int i = 0; i < 2; ++i) {
        int s = tid * 2 + i;
        int r = s >> 3, off = (s & 7) << 3;
        *(half8*)(dst + r * LDSP + off) =
            *(const half8*)(src + (size_t)(row0 + r) * ld + k0 + off);
    }
}
__device__ __forceinline__ void mfma_tile(const _Float16* As, const _Float16* Bs,
                                          f32x4 acc[2][2], int wm, int wn, int x, int qq) {
#pragma unroll
    for (int ks = 0; ks < 2; ++ks) {
        int kof = ks * 32 + qq * 8;
        half8 a0 = *(const half8*)(As + (wm + x) * LDSP + kof);
        half8 a1 = *(const half8*)(As + (wm + 16 + x) * LDSP + kof);
        half8 b0 = *(const half8*)(Bs + (wn + x) * LDSP + kof);
        half8 b1 = *(const half8*)(Bs + (wn + 16 + x) * LDSP + kof);
        acc[0][0] = __builtin_amdgcn_mfma_f32_16x16x32_f16(a0, b0, acc[0][0], 0, 0, 0);
        acc[0][1] = __builtin_amdgcn_mfma_f32_16x16x32_f16(a0, b1, acc[0][1], 0, 0, 0);
        acc[1][0] = __builtin_amdgcn_mfma_f32_16x16x32_f16(a1, b0, acc[1][0], 0, 0, 0);
        acc[1][1] = __builtin_amdgcn_mfma_f32_16x16x32_f16(a1, b1, acc[1][1], 0, 0, 0);
    }
}
#define WAVE_IDX()                             \
    int tid = threadIdx.x;                     \
    int wave = tid >> 6, lane = tid & 63;      \
    int wm = (wave >> 1) * 32, wn = (wave & 1) * 32; \
    int x = lane & 15, qq = lane >> 4;
#define ACC_INIT()                             \
    f32x4 zf = {0.f, 0.f, 0.f, 0.f};           \
    f32x4 acc[2][2];                           \
    acc[0][0] = zf; acc[0][1] = zf; acc[1][0] = zf; acc[1][1] = zf;

// ------------------------- prep kernels -------------------------
__global__ __launch_bounds__(256) void k_cast_multi(const float* __restrict__ s0,
                                                    const float* __restrict__ s1,
                                                    const float* __restrict__ s2,
                                                    _Float16* __restrict__ d0,
                                                    _Float16* __restrict__ d1,
                                                    _Float16* __restrict__ d2, int n) {
    const float* s = blockIdx.y == 0 ? s0 : (blockIdx.y == 1 ? s1 : s2);
    _Float16* d = blockIdx.y == 0 ? d0 : (blockIdx.y == 1 ? d1 : d2);
    for (int i = blockIdx.x * 256 + threadIdx.x; i < n; i += gridDim.x * 256)
        d[i] = (_Float16)s[i];
}

__global__ __launch_bounds__(256) void k_repack_conv2(const float* __restrict__ w1,
                                                      const float* __restrict__ w2,
                                                      _Float16* __restrict__ d1,
                                                      _Float16* __restrict__ d2) {
    const float* w = blockIdx.y ? w2 : w1;
    _Float16* dst = blockIdx.y ? d2 : d1;
    int i = blockIdx.x * 256 + threadIdx.x;
    if (i >= 9 * CC * CC) return;
    int r = i / (CC * CC);
    int rem = i - r * CC * CC;
    int co = rem / CC, ci = rem - (rem / CC) * CC;
    dst[i] = (_Float16)w[((size_t)co * CC + ci) * 9 + r];
}

__global__ __launch_bounds__(256) void k_transpose_x(const float* __restrict__ x,
                                                     _Float16* __restrict__ xT) {
    __shared__ float tile[32][33];
    int b = blockIdx.z;
    int c0 = blockIdx.y * 32, n0 = blockIdx.x * 32;
    int tx = threadIdx.x & 31, ty = threadIdx.x >> 5;
    const float* xb = x + (size_t)b * CC * NN;
#pragma unroll
    for (int rr = 0; rr < 32; rr += 8)
        tile[ty + rr][tx] = xb[(size_t)(c0 + ty + rr) * NN + n0 + tx];
    __syncthreads();
    _Float16* xTb = xT + (size_t)b * NN * CC;
#pragma unroll
    for (int rr = 0; rr < 32; rr += 8)
        xTb[(size_t)(n0 + ty + rr) * CC + c0 + tx] = (_Float16)tile[tx][ty + rr];
}

// ------------------------- q/k projection -------------------------
__global__ __launch_bounds__(256) void k_qkproj(const _Float16* __restrict__ Wq,
                                                const _Float16* __restrict__ Wk,
                                                const float* __restrict__ bq,
                                                const float* __restrict__ bk,
                                                const _Float16* __restrict__ xT,
                                                _Float16* __restrict__ qT,
                                                _Float16* __restrict__ kT) {
    __shared__ _Float16 As[64 * LDSP];
    __shared__ _Float16 Bs[64 * LDSP];
    WAVE_IDX();
    int j0 = blockIdx.x * 64, b = blockIdx.z;
    const _Float16* Wp = blockIdx.y ? Wk : Wq;
    const float* bias = blockIdx.y ? bk : bq;
    _Float16* outT = blockIdx.y ? kT : qT;
    const _Float16* xTb = xT + (size_t)b * NN * CC;
    ACC_INIT();
    for (int kc = 0; kc < CC; kc += 64) {
        stage_rows(As, Wp, CC, 0, kc, tid);
        stage_rows(Bs, xTb, CC, j0, kc, tid);
        __syncthreads();
        mfma_tile(As, Bs, acc, wm, wn, x, qq);
        __syncthreads();
    }
#pragma unroll
    for (int ms = 0; ms < 2; ++ms) {
        int R0 = wm + ms * 16 + qq * 4;
#pragma unroll
        for (int ns = 0; ns < 2; ++ns) {
            int Ccol = j0 + wn + ns * 16 + x;
            half4 t;
            t.x = (_Float16)(acc[ms][ns][0] + bias[R0 + 0]);
            t.y = (_Float16)(acc[ms][ns][1] + bias[R0 + 1]);
            t.z = (_Float16)(acc[ms][ns][2] + bias[R0 + 2]);
            t.w = (_Float16)(acc[ms][ns][3] + bias[R0 + 3]);
            *(half4*)(outT + ((size_t)b * NN + Ccol) * DDQ + R0) = t;
        }
    }
}

// ------------------------- C x C GEMM, big tile (out: bf16) -------------------------
template <int EPI, int PAD>
__global__ __launch_bounds__(256) void k_cgemm(const _Float16* __restrict__ W,
                                               const float* __restrict__ bias,
                                               const _Float16* __restrict__ Bsrc,
                                               const float* __restrict__ gate,
                                               unsigned short* __restrict__ out) {
    __shared__ _Float16 As[128 * 64];
    __shared__ _Float16 Bs[64 * 64];
    BWAVE_IDX();
    int j0 = blockIdx.x * 64, i0 = blockIdx.y * 128, b = blockIdx.z;
    const _Float16* Bb = Bsrc + (size_t)b * (PAD ? (size_t)PROWS * CC : (size_t)NN * CC);

    const _Float16* aSrc[4]; int aOf[4];
#pragma unroll
    for (int i = 0; i < 4; ++i) {
        SLOT_A(i);
        aSrc[i] = W + (size_t)(i0 + r) * CC + koff;
        aOf[i] = sb * 8;
    }
    const _Float16* bSrc[2]; int bOf[2];
#pragma unroll
    for (int i = 0; i < 2; ++i) {
        SLOT_B(i);
        int row = PAD ? prow(j0 + r) : (j0 + r);
        bSrc[i] = Bb + (size_t)row * CC + koff;
        bOf[i] = sb * 8;
    }
    BACC_INIT();
    for (int kc = 0; kc < CC; kc += 64) {
        __syncthreads();
#pragma unroll
        for (int i = 0; i < 4; ++i) gl16(aSrc[i] + kc, As + aOf[i]);
#pragma unroll
        for (int i = 0; i < 2; ++i) gl16(bSrc[i] + kc, Bs + bOf[i]);
        __syncthreads();
        btile(As, Bs, acc, wm, wn, x, qq);
    }
#pragma unroll
    for (int mt = 0; mt < 4; ++mt) {
        int R0 = i0 + wm + mt * 16 + qq * 4;
#pragma unroll
        for (int nt = 0; nt < 2; ++nt) {
            int Ccol = j0 + wn + nt * 16 + x;
#pragma unroll
            for (int e = 0; e < 4; ++e) {
                float v = acc[mt][nt][e] + bias[R0 + e];
                size_t idx = ((size_t)b * CC + R0 + e) * NN + Ccol;
                if (EPI == 1) v = gate[idx] / (1.f + __expf(-v));
                out[idx] = f2bf(v);
            }
        }
    }
}

// ------------------------- energy -> exp -> bf16 + row sums -------------------------
// Grid (36 ktiles, 36 qtiles, B). Each block: one 64x64 tile of exp(masked e),
// stored UNNORMALIZED bf16 (range safe: exp(|e|<40) << bf16 max), plus per-row
// partial sums atomically added to rowsum[b][m]. Normalization happens in k_attn.
__global__ __launch_bounds__(256) void k_exp(const _Float16* __restrict__ qT,
                                             const _Float16* __restrict__ kT,
                                             unsigned short* __restrict__ attnB,
                                             float* __restrict__ rowsum, int rad) {
    __shared__ _Float16 qs[64 * LDSP];
    __shared__ _Float16 ks[64 * LDSP];
    __shared__ unsigned short Eh[64 * 72];
    __shared__ float psum[512];
    WAVE_IDX();
    int j0 = blockIdx.x * 64, i0 = blockIdx.y * 64, b = blockIdx.z;
    if (rad > 0) {
        int hlo = i0 / WW, hhi = (i0 + 63) / WW;
        int h2lo = imax(0, hlo - rad), h2hi = imin(HH - 1, hhi + rad);
        int klo = (h2lo * WW) & ~63;
        int khi = imin(NN, ((h2hi + 1) * WW + 63) & ~63);
        if (j0 + 64 <= klo || j0 >= khi) return;
    }
    stage_rows(qs, qT + (size_t)b * NN * DDQ, DDQ, i0, 0, tid);
    stage_rows(ks, kT + (size_t)b * NN * DDQ, DDQ, j0, 0, tid);
    __syncthreads();
    ACC_INIT();
    mfma_tile(qs, ks, acc, wm, wn, x, qq);
#pragma unroll
    for (int ns = 0; ns < 2; ++ns) {
        int col = wn + ns * 16 + x;
        int gn = j0 + col;
        int hn = gn / WW, cn = gn % WW;
#pragma unroll
        for (int ms = 0; ms < 2; ++ms)
#pragma unroll
            for (int e = 0; e < 4; ++e) {
                int row = wm + ms * 16 + qq * 4 + e;
                int gm = i0 + row;
                bool valid = true;
                if (rad > 0) {
                    int dh = gm / WW - hn; if (dh < 0) dh = -dh;
                    int dc = gm % WW - cn; if (dc < 0) dc = -dc;
                    valid = (dh <= rad) && (dc <= rad);
                }
                float w = valid ? __expf(acc[ms][ns][e]) : 0.f;
                Eh[row * 72 + col] = f2bf(w);
            }
    }
    __syncthreads();
    // coalesced store + per-(row, 8-col) partial sums
#pragma unroll
    for (int t = 0; t < 2; ++t) {
        int s = tid + t * 256;
        int r = s >> 3, cg = (s & 7) << 3;
        bf16x8 v = *(const bf16x8*)(Eh + r * 72 + cg);
        *(bf16x8*)(attnB + ((size_t)b * NN + i0 + r) * NN + j0 + cg) = v;
        float ss = 0.f;
#pragma unroll
        for (int j = 0; j < 8; ++j) ss += bf2f((unsigned short)v[j]);
        psum[s] = ss;
    }
    __syncthreads();
    if (tid < 64) {
        float tot = 0.f;
#pragma unroll
        for (int g = 0; g < 8; ++g) tot += psum[tid * 8 + g];
        atomicAdd(rowsum + (size_t)b * NN + i0 + tid, tot);
    }
}

// ------------------------- attention apply, big tile, bf16 -------------------------
// out[c][m] = gamma * (sum_n A[c][n]*w[m][n]) / rowsum[m] + res[c][m]
__global__ __launch_bounds__(256) void k_attn(const unsigned short* __restrict__ A,
                                              const unsigned short* __restrict__ attnB,
                                              const float* __restrict__ rowsum,
                                              const float* __restrict__ res,
                                              const float* __restrict__ gamma,
                                              float* __restrict__ outF,
                                              _Float16* __restrict__ outT, int rad) {
    __shared__ unsigned short As[128 * 64];
    __shared__ unsigned short Bs[64 * 64];
    BWAVE_IDX();
    int j0 = blockIdx.x * 64, i0 = blockIdx.y * 128, b = blockIdx.z;
    int klo = 0, khi = NN;
    if (rad > 0) {
        int hlo = j0 / WW, hhi = (j0 + 63) / WW;
        int h2lo = imax(0, hlo - rad), h2hi = imin(HH - 1, hhi + rad);
        klo = (h2lo * WW) & ~63;
        khi = imin(NN, ((h2hi + 1) * WW + 63) & ~63);
    }
    const unsigned short* Ab = A + (size_t)b * CC * NN;
    const unsigned short* Tb = attnB + (size_t)b * NN * NN;

    const unsigned short* aSrc[4]; int aOf[4];
#pragma unroll
    for (int i = 0; i < 4; ++i) {
        SLOT_A(i);
        aSrc[i] = Ab + (size_t)(i0 + r) * NN + koff;
        aOf[i] = sb * 8;
    }
    const unsigned short* bSrc[2]; int bOf[2];
#pragma unroll
    for (int i = 0; i < 2; ++i) {
        SLOT_B(i);
        bSrc[i] = Tb + (size_t)(j0 + r) * NN + koff;
        bOf[i] = sb * 8;
    }
    BACC_INIT();
    for (int kc = klo; kc < khi; kc += 64) {
        __syncthreads();
#pragma unroll
        for (int i = 0; i < 4; ++i) gl16(aSrc[i] + kc, As + aOf[i]);
#pragma unroll
        for (int i = 0; i < 2; ++i) gl16(bSrc[i] + kc, Bs + bOf[i]);
        __syncthreads();
        btile_b(As, Bs, acc, wm, wn, x, qq);
    }
    float g = gamma[0];
#pragma unroll
    for (int mt = 0; mt < 4; ++mt) {
        int R0 = i0 + wm + mt * 16 + qq * 4;
#pragma unroll
        for (int nt = 0; nt < 2; ++nt) {
            int Ccol = j0 + wn + nt * 16 + x;
            float linv = g / fmaxf(rowsum[(size_t)b * NN + Ccol], 1e-30f);
            float v[4];
#pragma unroll
            for (int e = 0; e < 4; ++e)
                v[e] = acc[mt][nt][e] * linv + res[((size_t)b * CC + R0 + e) * NN + Ccol];
            if (outT) {
                half4 t;
                t.x = (_Float16)v[0]; t.y = (_Float16)v[1];
                t.z = (_Float16)v[2]; t.w = (_Float16)v[3];
                *(half4*)(outT + ((size_t)b * PROWS + prow(Ccol)) * CC + R0) = t;
            }
            if (outF) {
#pragma unroll
                for (int e = 0; e < 4; ++e)
                    outF[((size_t)b * CC + R0 + e) * NN + Ccol] = v[e];
            }
        }
    }
}

// ------------------------- 3x3 conv, big tile, fused BN+ReLU -------------------------
__global__ __launch_bounds__(256) void k_conv3(const _Float16* __restrict__ Arep,
                                               const _Float16* __restrict__ Tpad,
                                               const float* __restrict__ bng,
                                               const float* __restrict__ bnb,
                                               const float* __restrict__ bnm,
                                               const float* __restrict__ bnv,
                                               float* __restrict__ outF,
                                               _Float16* __restrict__ outT) {
    __shared__ _Float16 As[128 * 64];
    __shared__ _Float16 Bs[64 * 64];
    BWAVE_IDX();
    int j0 = blockIdx.x * 64, i0 = blockIdx.y * 128, b = blockIdx.z;
    const _Float16* Tb = Tpad + (size_t)b * PROWS * CC;

    size_t aRow[4]; int aOf[4];
#pragma unroll
    for (int i = 0; i < 4; ++i) {
        SLOT_A(i);
        aRow[i] = (size_t)(i0 + r) * CC + koff;
        aOf[i] = sb * 8;
    }
    int bPr[2], bKoff[2], bOf[2];
#pragma unroll
    for (int i = 0; i < 2; ++i) {
        SLOT_B(i);
        bPr[i] = prow(j0 + r);
        bKoff[i] = koff;
        bOf[i] = sb * 8;
    }
    BACC_INIT();
#pragma unroll
    for (int rt = 0; rt < 9; ++rt) {
        int dh = rt / 3 - 1, dw = rt - (rt / 3) * 3 - 1;
        int shift = dh * PW + dw;
        const _Float16* Ar = Arep + (size_t)rt * CC * CC;
        for (int ci0 = 0; ci0 < CC; ci0 += 64) {
            __syncthreads();
#pragma unroll
            for (int i = 0; i < 4; ++i) gl16(Ar + aRow[i] + ci0, As + aOf[i]);
#pragma unroll
            for (int i = 0; i < 2; ++i)
                gl16(Tb + (size_t)(bPr[i] + shift) * CC + ci0 + bKoff[i], Bs + bOf[i]);
            __syncthreads();
            btile(As, Bs, acc, wm, wn, x, qq);
        }
    }
#pragma unroll
    for (int mt = 0; mt < 4; ++mt) {
        int R0 = i0 + wm + mt * 16 + qq * 4;
        float sc[4], sh[4];
#pragma unroll
        for (int e = 0; e < 4; ++e) {
            sc[e] = bng[R0 + e] * rsqrtf(bnv[R0 + e] + 1e-5f);
            sh[e] = bnb[R0 + e] - bnm[R0 + e] * sc[e];
        }
#pragma unroll
        for (int nt = 0; nt < 2; ++nt) {
            int Ccol = j0 + wn + nt * 16 + x;
            float v[4];
#pragma unroll
            for (int e = 0; e < 4; ++e) {
                float t = acc[mt][nt][e] * sc[e] + sh[e];
                v[e] = t > 0.f ? t : 0.f;
                outF[((size_t)b * CC + R0 + e) * NN + Ccol] = v[e];
            }
            half4 t4;
            t4.x = (_Float16)v[0]; t4.y = (_Float16)v[1];
            t4.z = (_Float16)v[2]; t4.w = (_Float16)v[3];
            *(half4*)(outT + ((size_t)b * PROWS + prow(Ccol)) * CC + R0) = t4;
        }
    }
}

// ---------------------------------------------------------------------------
extern "C" void kernel_launch(void* const* d_in, const int* in_sizes, int n_in,
                              void* d_out, int out_size, void* d_ws, size_t ws_size,
                              hipStream_t stream) {
    const float* xin  = (const float*)d_in[0];
    const float* Wq   = (const float*)d_in[1];
    const float* bq   = (const float*)d_in[2];
    const float* Wk   = (const float*)d_in[3];
    const float* bk   = (const float*)d_in[4];
    const float* Wv   = (const float*)d_in[5];
    const float* bv   = (const float*)d_in[6];
    const float* c1w  = (const float*)d_in[7];
    const float* bn1w = (const float*)d_in[8];
    const float* bn1b = (const float*)d_in[9];
    const float* bn1m = (const float*)d_in[10];
    const float* bn1v = (const float*)d_in[11];
    const float* c2w  = (const float*)d_in[12];
    const float* bn2w = (const float*)d_in[13];
    const float* bn2b = (const float*)d_in[14];
    const float* bn2m = (const float*)d_in[15];
    const float* bn2v = (const float*)d_in[16];
    const float* s1w  = (const float*)d_in[17];
    const float* s1b  = (const float*)d_in[18];
    const float* s2w  = (const float*)d_in[19];
    const float* s2b  = (const float*)d_in[20];
    const float* gamma  = (const float*)d_in[21];
    const float* gamma1 = (const float*)d_in[22];
    const float* gamma2 = (const float*)d_in[23];

    float* out = (float*)d_out;

    char* p = (char*)d_ws;
    unsigned short* attn = (unsigned short*)p; p += (size_t)BB * NN * NN * 2;  // 42.5 MB
    _Float16* xT    = (_Float16*)p; p += (size_t)BB * NN * CC * 2;      // 9.4 MB
    _Float16* qT    = (_Float16*)p; p += (size_t)BB * NN * DDQ * 2;
    _Float16* kT    = (_Float16*)p; p += (size_t)BB * NN * DDQ * 2;
    unsigned short* vsB = (unsigned short*)p; p += (size_t)BB * CC * NN * 2;  // 9.4 MB
    _Float16* TattnP= (_Float16*)p; p += (size_t)BB * PROWS * CC * 2;   // 10.2 MB
    _Float16* TconvP= (_Float16*)p; p += (size_t)BB * PROWS * CC * 2;   // 10.2 MB
    float*    rR    = (float*)p;    p += (size_t)BB * CC * NN * 4;      // 18.9 MB
    _Float16* wq_h  = (_Float16*)p; p += (size_t)DDQ * CC * 2;
    _Float16* wk_h  = (_Float16*)p; p += (size_t)DDQ * CC * 2;
    _Float16* wv_h  = (_Float16*)p; p += (size_t)CC * CC * 2;
    _Float16* s1_h  = (_Float16*)p; p += (size_t)CC * CC * 2;
    _Float16* s2_h  = (_Float16*)p; p += (size_t)CC * CC * 2;
    _Float16* crep1 = (_Float16*)p; p += (size_t)9 * CC * CC * 2;
    _Float16* crep2 = (_Float16*)p; p += (size_t)9 * CC * CC * 2;
    float*    rowsum= (float*)p;    p += (size_t)3 * BB * NN * 4;       // 110 KB (3 stages)

    dim3 blk(256);

    // zero padded activation borders + rowsums
    hipMemsetAsync(TattnP, 0, (size_t)BB * PROWS * CC * 2, stream);
    hipMemsetAsync(TconvP, 0, (size_t)BB * PROWS * CC * 2, stream);
    hipMemsetAsync(rowsum, 0, (size_t)3 * BB * NN * 4, stream);

    // ---- prep ----
    k_cast_multi<<<dim3(128, 2), blk, 0, stream>>>(Wq, Wk, nullptr, wq_h, wk_h, nullptr, DDQ * CC);
    k_cast_multi<<<dim3(1024, 3), blk, 0, stream>>>(Wv, s1w, s2w, wv_h, s1_h, s2_h, CC * CC);
    k_repack_conv2<<<dim3((9 * CC * CC + 255) / 256, 2), blk, 0, stream>>>(c1w, c2w, crep1, crep2);
    k_transpose_x<<<dim3(NN / 32, CC / 32, BB), blk, 0, stream>>>(xin, xT);

    dim3 gQK(NN / 64, 2, BB);
    dim3 gExp(NN / 64, NN / 64, BB);    // (36, 36, 4) = 5184 blocks
    dim3 gBig(NN / 64, CC / 128, BB);   // (36, 4, 4) = 576 blocks

    float* rs0 = rowsum;
    float* rs1 = rowsum + (size_t)BB * NN;
    float* rs2 = rowsum + (size_t)2 * BB * NN;

    // projections
    k_qkproj<<<gQK, blk, 0, stream>>>(wq_h, wk_h, bq, bk, xT, qT, kT);
    k_cgemm<0, 0><<<gBig, blk, 0, stream>>>(wv_h, bv, xT, nullptr, vsB);

    // ---- stage 0: dense attention ----
    k_exp<<<gExp, blk, 0, stream>>>(qT, kT, attn, rs0, -1);
    k_attn<<<gBig, blk, 0, stream>>>(vsB, attn, rs0, xin, gamma, nullptr, TattnP, -1);
    k_conv3<<<gBig, blk, 0, stream>>>(crep1, TattnP, bn1w, bn1b, bn1m, bn1v, rR, TconvP);

    // ---- stage 1: radius-6 masked attention ----
    k_cgemm<1, 1><<<gBig, blk, 0, stream>>>(s1_h, s1b, TconvP, rR, vsB);
    k_exp<<<gExp, blk, 0, stream>>>(qT, kT, attn, rs1, 6);
    k_attn<<<gBig, blk, 0, stream>>>(vsB, attn, rs1, rR, gamma1, nullptr, TattnP, 6);
    k_conv3<<<gBig, blk, 0, stream>>>(crep2, TattnP, bn2w, bn2b, bn2m, bn2v, rR, TconvP);

    // ---- stage 2: radius-12 masked attention ----
    k_cgemm<1, 1><<<gBig, blk, 0, stream>>>(s2_h, s2b, TconvP, rR, vsB);
    k_exp<<<gExp, blk, 0, stream>>>(qT, kT, attn, rs2, 12);
    k_attn<<<gBig, blk, 0, stream>>>(vsB, attn, rs2, rR, gamma2, out, nullptr, 12);
}